// Round 1
// baseline (1273.400 us; speedup 1.0000x reference)
//
#include <hip/hip_runtime.h>
#include <stdint.h>

typedef float  f32x4  __attribute__((ext_vector_type(4)));
typedef __bf16 bf16x8 __attribute__((ext_vector_type(8)));
typedef unsigned int   u32;
typedef unsigned short u16;
typedef unsigned long long u64;
typedef u32 u32x4 __attribute__((ext_vector_type(4)));

#define M_TOT 8192
#define N_TOT 4096
#define K_DIN 4096
#define RANK  32

__device__ __forceinline__ u16 f2bf(float f) {
  union { float f; u32 u; } v; v.f = f;
  u32 r = v.u + 0x7fffu + ((v.u >> 16) & 1u);
  return (u16)(r >> 16);
}

// ---- P0: a_s[r][k] = lora_a[r][k] * smooth[k]  (fp32, 32x4096)
__global__ void prep_as_k(const float* __restrict__ la, const float* __restrict__ ss,
                          float* __restrict__ a_s) {
  int i = blockIdx.x * 256 + threadIdx.x;           // float4 index (32768 total)
  f32x4 v = ((const f32x4*)la)[i];
  f32x4 s = ((const f32x4*)ss)[i & 1023];
  ((f32x4*)a_s)[i] = v * s;
}

// ---- generic fp32 -> bf16 cast (4/thread)
__global__ void cvt_bf16_k(const float* __restrict__ in, u16* __restrict__ out, int n4) {
  int i = blockIdx.x * 256 + threadIdx.x;
  if (i >= n4) return;
  f32x4 v = ((const f32x4*)in)[i];
  alignas(8) u16 o[4] = { f2bf(v[0]), f2bf(v[1]), f2bf(v[2]), f2bf(v[3]) };
  *(u64*)(out + 4 * (size_t)i) = *(const u64*)o;
}

// ---- P1: smooth + blockwise fake-quant -> xq (bf16); raw x -> xb (bf16)
// one thread = one 16-element quant block; fp32 math bit-matches numpy (RNE rint, IEEE div)
__global__ void prep_x_k(const float* __restrict__ x, const float* __restrict__ ss,
                         u16* __restrict__ xq, u16* __restrict__ xb) {
  int m = blockIdx.x;
  int t = threadIdx.x;                                // 256 threads * 16 = 4096
  size_t off = (size_t)m * K_DIN + t * 16;
  const f32x4* xp = (const f32x4*)(x + off);
  const f32x4* sp = (const f32x4*)(ss + t * 16);
  float xs[16];
  alignas(16) u16 rb[16], qb[16];
  float amax = 0.0f;
  #pragma unroll
  for (int i = 0; i < 4; ++i) {
    f32x4 a = xp[i], s = sp[i];
    #pragma unroll
    for (int j = 0; j < 4; ++j) {
      float xr = a[j];
      float v  = xr * s[j];
      xs[i*4+j] = v;
      amax = fmaxf(amax, fabsf(v));
      rb[i*4+j] = f2bf(xr);
    }
  }
  amax = fmaxf(amax, 1e-12f);
  float scale = amax / 7.0f;                          // IEEE fp32 div (no fast-math)
  #pragma unroll
  for (int i = 0; i < 16; ++i) {
    float r = rintf(xs[i] / scale);                   // RNE, matches jnp.round
    r = fminf(7.0f, fmaxf(-7.0f, r));
    qb[i] = f2bf(r * scale);
  }
  ((u32x4*)(xq + off))[0] = ((const u32x4*)qb)[0];
  ((u32x4*)(xq + off))[1] = ((const u32x4*)qb)[1];
  ((u32x4*)(xb + off))[0] = ((const u32x4*)rb)[0];
  ((u32x4*)(xb + off))[1] = ((const u32x4*)rb)[1];
}

// ---- P2: t[m][r] = sum_k x[m][k] * a_s[r][k]   (fp32 accumulate, bf16 out)
__global__ void lora_t_k(const float* __restrict__ x, const float* __restrict__ a_s,
                         u16* __restrict__ tb) {
  int m = blockIdx.x * 8 + (threadIdx.x >> 5);
  int r = threadIdx.x & 31;
  const f32x4* xr = (const f32x4*)(x + (size_t)m * K_DIN);
  const f32x4* ar = (const f32x4*)(a_s + (size_t)r * K_DIN);
  float acc = 0.0f;
  #pragma unroll 4
  for (int k = 0; k < K_DIN / 4; ++k) {
    f32x4 xv = xr[k], av = ar[k];
    acc += xv[0]*av[0] + xv[1]*av[1] + xv[2]*av[2] + xv[3]*av[3];
  }
  tb[(size_t)m * RANK + r] = f2bf(acc);
}

// ---- main GEMM: C[8192][4096] = [xq|xb|t] @ [wq|ws|lb]^T + bias
#define BM 128
#define BN 128
#define BK 32

__device__ __forceinline__ void gld_lds16(const u16* g, u16* l) {
  __builtin_amdgcn_global_load_lds((const __attribute__((address_space(1))) u32*)g,
                                   (__attribute__((address_space(3))) u32*)l,
                                   16, 0, 0);
}

__global__ __launch_bounds__(256, 3)
void gemm_k(const u16* __restrict__ xq, const u16* __restrict__ xb,
            const u16* __restrict__ tb, const u16* __restrict__ wqb,
            const u16* __restrict__ wsb, const u16* __restrict__ lbb,
            const float* __restrict__ bias, float* __restrict__ out) {
  __shared__ u16 As[BM * BK];   // [m][k], k contiguous (64B rows)
  __shared__ u16 Bs[BN * BK];   // [n][k]
  const int tid  = threadIdx.x;
  const int wave = tid >> 6;
  const int lane = tid & 63;
  const int m0 = blockIdx.y * BM;
  const int n0 = blockIdx.x * BN;
  const int wr = wave >> 1, wc = wave & 1;
  const int lr = lane & 15, lg = lane >> 4;

  f32x4 acc[4][4] = {};

  // staging: each thread covers one 16B chunk per half-tile (rows 0-63, 64-127)
  const int sm = tid >> 2;            // row within 64-row half
  const int sk = (tid & 3) * 8;       // k element offset
  u16* aDst0 = As + wave * 512;
  u16* aDst1 = As + 2048 + wave * 512;
  u16* bDst0 = Bs + wave * 512;
  u16* bDst1 = Bs + 2048 + wave * 512;
  const size_t a4 = (size_t)(m0 + sm) * 4096 + sk;
  const size_t b4 = (size_t)(n0 + sm) * 4096 + sk;

  for (int kt = 0; kt < (2 * K_DIN + RANK) / BK; ++kt) {
    const int k0 = kt * BK;
    const u16 *ga0, *ga1, *gb0, *gb1;
    if (k0 < 2 * K_DIN) {
      const u16* Ap = (k0 < K_DIN) ? xq : xb;
      const u16* Bp = (k0 < K_DIN) ? wqb : wsb;
      const int kl = k0 & (K_DIN - 1);
      ga0 = Ap + a4 + kl;  ga1 = Ap + a4 + (size_t)64 * 4096 + kl;
      gb0 = Bp + b4 + kl;  gb1 = Bp + b4 + (size_t)64 * 4096 + kl;
    } else {
      ga0 = tb  + (size_t)(m0 + sm) * RANK + sk;  ga1 = ga0 + 64 * RANK;
      gb0 = lbb + (size_t)(n0 + sm) * RANK + sk;  gb1 = gb0 + 64 * RANK;
    }
    gld_lds16(ga0, aDst0);
    gld_lds16(ga1, aDst1);
    gld_lds16(gb0, bDst0);
    gld_lds16(gb1, bDst1);
    __syncthreads();                     // compiler drains vmcnt before barrier

    bf16x8 af[4], bfr[4];
    #pragma unroll
    for (int i = 0; i < 4; ++i) {
      af[i]  = *(const bf16x8*)(As + (wr*64 + i*16 + lr) * BK + lg*8);
      bfr[i] = *(const bf16x8*)(Bs + (wc*64 + i*16 + lr) * BK + lg*8);
    }
    #pragma unroll
    for (int i = 0; i < 4; ++i)
      #pragma unroll
      for (int j = 0; j < 4; ++j)
        acc[i][j] = __builtin_amdgcn_mfma_f32_16x16x32_bf16(af[i], bfr[j], acc[i][j], 0, 0, 0);
    __syncthreads();
  }

  float bv[4];
  #pragma unroll
  for (int j = 0; j < 4; ++j) bv[j] = bias[n0 + wc*64 + j*16 + lr];
  #pragma unroll
  for (int i = 0; i < 4; ++i) {
    const int row = m0 + wr*64 + i*16 + lg*4;
    #pragma unroll
    for (int j = 0; j < 4; ++j) {
      const int col = n0 + wc*64 + j*16 + lr;
      float* op = out + (size_t)row * N_TOT + col;
      op[0 * (size_t)N_TOT] = acc[i][j][0] + bv[j];
      op[1 * (size_t)N_TOT] = acc[i][j][1] + bv[j];
      op[2 * (size_t)N_TOT] = acc[i][j][2] + bv[j];
      op[3 * (size_t)N_TOT] = acc[i][j][3] + bv[j];
    }
  }
}

extern "C" void kernel_launch(void* const* d_in, const int* in_sizes, int n_in,
                              void* d_out, int out_size, void* d_ws, size_t ws_size,
                              hipStream_t stream) {
  const float* x    = (const float*)d_in[0];
  const float* ss   = (const float*)d_in[1];
  const float* wq   = (const float*)d_in[2];
  const float* la   = (const float*)d_in[3];
  const float* lb   = (const float*)d_in[4];
  const float* wsp  = (const float*)d_in[5];
  const float* bias = (const float*)d_in[6];
  float* out = (float*)d_out;

  uint8_t* w = (uint8_t*)d_ws;
  u16* xq  = (u16*)w;  w += (size_t)M_TOT * K_DIN * 2;   // 64 MiB
  u16* xb  = (u16*)w;  w += (size_t)M_TOT * K_DIN * 2;   // 64 MiB
  u16* tb  = (u16*)w;  w += (size_t)M_TOT * RANK * 2;    // 0.5 MiB
  u16* wqb = (u16*)w;  w += (size_t)N_TOT * K_DIN * 2;   // 32 MiB
  u16* wsb = (u16*)w;  w += (size_t)N_TOT * K_DIN * 2;   // 32 MiB
  u16* lbb = (u16*)w;  w += (size_t)N_TOT * RANK * 2;    // 0.25 MiB
  float* a_s = (float*)w;                                 // 0.5 MiB

  prep_as_k<<<128, 256, 0, stream>>>(la, ss, a_s);
  cvt_bf16_k<<<16384, 256, 0, stream>>>(wq,  wqb, (N_TOT * K_DIN) / 4);
  cvt_bf16_k<<<16384, 256, 0, stream>>>(wsp, wsb, (N_TOT * K_DIN) / 4);
  cvt_bf16_k<<<128,   256, 0, stream>>>(lb,  lbb, (N_TOT * RANK) / 4);
  prep_x_k<<<M_TOT, 256, 0, stream>>>(x, ss, xq, xb);
  lora_t_k<<<M_TOT / 8, 256, 0, stream>>>(x, a_s, tb);
  gemm_k<<<dim3(N_TOT / BN, M_TOT / BM), 256, 0, stream>>>(xq, xb, tb, wqb, wsb, lbb, bias, out);
}

// Round 2
// 793.243 us; speedup vs baseline: 1.6053x; 1.6053x over previous
//
#include <hip/hip_runtime.h>
#include <stdint.h>

typedef float  f32x4  __attribute__((ext_vector_type(4)));
typedef __bf16 bf16x8 __attribute__((ext_vector_type(8)));
typedef unsigned int   u32;
typedef unsigned short u16;
typedef unsigned long long u64;
typedef u32 u32x4 __attribute__((ext_vector_type(4)));

#define M_TOT 8192
#define N_TOT 4096
#define K_DIN 4096
#define RANK  32

__device__ __forceinline__ u16 f2bf(float f) {
  union { float f; u32 u; } v; v.f = f;
  u32 r = v.u + 0x7fffu + ((v.u >> 16) & 1u);
  return (u16)(r >> 16);
}

// ---- P0: a_sb[r][k] = bf16(lora_a[r][k] * smooth[k])  (32x4096)
__global__ void prep_as_k(const float* __restrict__ la, const float* __restrict__ ss,
                          u16* __restrict__ asb) {
  int i = blockIdx.x * 256 + threadIdx.x;           // float4 index (32768 total)
  f32x4 v = ((const f32x4*)la)[i];
  f32x4 s = ((const f32x4*)ss)[i & 1023];
  f32x4 p = v * s;
  alignas(8) u16 o[4] = { f2bf(p[0]), f2bf(p[1]), f2bf(p[2]), f2bf(p[3]) };
  *(u64*)(asb + 4 * (size_t)i) = *(const u64*)o;
}

// ---- generic fp32 -> bf16 cast (4/thread)
__global__ void cvt_bf16_k(const float* __restrict__ in, u16* __restrict__ out, int n4) {
  int i = blockIdx.x * 256 + threadIdx.x;
  if (i >= n4) return;
  f32x4 v = ((const f32x4*)in)[i];
  alignas(8) u16 o[4] = { f2bf(v[0]), f2bf(v[1]), f2bf(v[2]), f2bf(v[3]) };
  *(u64*)(out + 4 * (size_t)i) = *(const u64*)o;
}

// ---- P1: smooth + blockwise fake-quant -> xq (bf16); raw x -> xb (bf16)
// one thread = one 16-element quant block; fp32 math bit-matches numpy (RNE rint, IEEE div)
__global__ void prep_x_k(const float* __restrict__ x, const float* __restrict__ ss,
                         u16* __restrict__ xq, u16* __restrict__ xb) {
  int m = blockIdx.x;
  int t = threadIdx.x;                                // 256 threads * 16 = 4096
  size_t off = (size_t)m * K_DIN + t * 16;
  const f32x4* xp = (const f32x4*)(x + off);
  const f32x4* sp = (const f32x4*)(ss + t * 16);
  float xs[16];
  alignas(16) u16 rb[16], qb[16];
  float amax = 0.0f;
  #pragma unroll
  for (int i = 0; i < 4; ++i) {
    f32x4 a = xp[i], s = sp[i];
    #pragma unroll
    for (int j = 0; j < 4; ++j) {
      float xr = a[j];
      float v  = xr * s[j];
      xs[i*4+j] = v;
      amax = fmaxf(amax, fabsf(v));
      rb[i*4+j] = f2bf(xr);
    }
  }
  amax = fmaxf(amax, 1e-12f);
  float scale = amax / 7.0f;                          // IEEE fp32 div (no fast-math)
  #pragma unroll
  for (int i = 0; i < 16; ++i) {
    float r = rintf(xs[i] / scale);                   // RNE, matches jnp.round
    r = fminf(7.0f, fmaxf(-7.0f, r));
    qb[i] = f2bf(r * scale);
  }
  ((u32x4*)(xq + off))[0] = ((const u32x4*)qb)[0];
  ((u32x4*)(xq + off))[1] = ((const u32x4*)qb)[1];
  ((u32x4*)(xb + off))[0] = ((const u32x4*)rb)[0];
  ((u32x4*)(xb + off))[1] = ((const u32x4*)rb)[1];
}

// ---- P2: t[m][r] = sum_k xb[m][k] * a_sb[r][k] via MFMA (bf16 in, fp32 acc)
// 4 waves/block, each wave owns 16 m-rows x 32 cols; a_sb (256 KiB) is L1/L2-resident.
__global__ __launch_bounds__(256)
void lora_t_mfma_k(const u16* __restrict__ xb, const u16* __restrict__ asb,
                   u16* __restrict__ tb) {
  const int wave = threadIdx.x >> 6;
  const int lane = threadIdx.x & 63;
  const int lr = lane & 15, lg = lane >> 4;
  const int m0 = blockIdx.x * 64 + wave * 16;
  f32x4 acc0 = {}, acc1 = {};
  for (int k0 = 0; k0 < K_DIN; k0 += 32) {
    bf16x8 a  = *(const bf16x8*)(xb  + (size_t)(m0 + lr) * K_DIN + k0 + lg * 8);
    bf16x8 b0 = *(const bf16x8*)(asb + (size_t)lr        * K_DIN + k0 + lg * 8);
    bf16x8 b1 = *(const bf16x8*)(asb + (size_t)(16 + lr) * K_DIN + k0 + lg * 8);
    acc0 = __builtin_amdgcn_mfma_f32_16x16x32_bf16(a, b0, acc0, 0, 0, 0);
    acc1 = __builtin_amdgcn_mfma_f32_16x16x32_bf16(a, b1, acc1, 0, 0, 0);
  }
  // C/D layout: col = lane&15, row = (lane>>4)*4 + j
  #pragma unroll
  for (int j = 0; j < 4; ++j) {
    const int row = m0 + lg * 4 + j;
    tb[(size_t)row * RANK + lr]      = f2bf(acc0[j]);
    tb[(size_t)row * RANK + 16 + lr] = f2bf(acc1[j]);
  }
}

// ---- main GEMM: C[8192][4096] = [xq|xb|t] @ [wq|ws|lb]^T + bias
#define BM 128
#define BN 128
#define BK 32

__device__ __forceinline__ void gld_lds16(const u16* g, u16* l) {
  __builtin_amdgcn_global_load_lds((const __attribute__((address_space(1))) u32*)g,
                                   (__attribute__((address_space(3))) u32*)l,
                                   16, 0, 0);
}

__global__ __launch_bounds__(256, 3)
void gemm_k(const u16* __restrict__ xq, const u16* __restrict__ xb,
            const u16* __restrict__ tb, const u16* __restrict__ wqb,
            const u16* __restrict__ wsb, const u16* __restrict__ lbb,
            const float* __restrict__ bias, float* __restrict__ out) {
  __shared__ u16 As[BM * BK];   // [m][k], k contiguous (64B rows)
  __shared__ u16 Bs[BN * BK];   // [n][k]
  const int tid  = threadIdx.x;
  const int wave = tid >> 6;
  const int lane = tid & 63;
  const int m0 = blockIdx.y * BM;
  const int n0 = blockIdx.x * BN;
  const int wr = wave >> 1, wc = wave & 1;
  const int lr = lane & 15, lg = lane >> 4;

  f32x4 acc[4][4] = {};

  // staging: each thread covers one 16B chunk per half-tile (rows 0-63, 64-127)
  const int sm = tid >> 2;            // row within 64-row half
  const int sk = (tid & 3) * 8;       // k element offset
  u16* aDst0 = As + wave * 512;
  u16* aDst1 = As + 2048 + wave * 512;
  u16* bDst0 = Bs + wave * 512;
  u16* bDst1 = Bs + 2048 + wave * 512;
  const size_t a4 = (size_t)(m0 + sm) * 4096 + sk;
  const size_t b4 = (size_t)(n0 + sm) * 4096 + sk;

  for (int kt = 0; kt < (2 * K_DIN + RANK) / BK; ++kt) {
    const int k0 = kt * BK;
    const u16 *ga0, *ga1, *gb0, *gb1;
    if (k0 < 2 * K_DIN) {
      const u16* Ap = (k0 < K_DIN) ? xq : xb;
      const u16* Bp = (k0 < K_DIN) ? wqb : wsb;
      const int kl = k0 & (K_DIN - 1);
      ga0 = Ap + a4 + kl;  ga1 = Ap + a4 + (size_t)64 * 4096 + kl;
      gb0 = Bp + b4 + kl;  gb1 = Bp + b4 + (size_t)64 * 4096 + kl;
    } else {
      ga0 = tb  + (size_t)(m0 + sm) * RANK + sk;  ga1 = ga0 + 64 * RANK;
      gb0 = lbb + (size_t)(n0 + sm) * RANK + sk;  gb1 = gb0 + 64 * RANK;
    }
    gld_lds16(ga0, aDst0);
    gld_lds16(ga1, aDst1);
    gld_lds16(gb0, bDst0);
    gld_lds16(gb1, bDst1);
    __syncthreads();                     // compiler drains vmcnt before barrier

    bf16x8 af[4], bfr[4];
    #pragma unroll
    for (int i = 0; i < 4; ++i) {
      af[i]  = *(const bf16x8*)(As + (wr*64 + i*16 + lr) * BK + lg*8);
      bfr[i] = *(const bf16x8*)(Bs + (wc*64 + i*16 + lr) * BK + lg*8);
    }
    #pragma unroll
    for (int i = 0; i < 4; ++i)
      #pragma unroll
      for (int j = 0; j < 4; ++j)
        acc[i][j] = __builtin_amdgcn_mfma_f32_16x16x32_bf16(af[i], bfr[j], acc[i][j], 0, 0, 0);
    __syncthreads();
  }

  float bv[4];
  #pragma unroll
  for (int j = 0; j < 4; ++j) bv[j] = bias[n0 + wc*64 + j*16 + lr];
  #pragma unroll
  for (int i = 0; i < 4; ++i) {
    const int row = m0 + wr*64 + i*16 + lg*4;
    #pragma unroll
    for (int j = 0; j < 4; ++j) {
      const int col = n0 + wc*64 + j*16 + lr;
      float* op = out + (size_t)row * N_TOT + col;
      op[0 * (size_t)N_TOT] = acc[i][j][0] + bv[j];
      op[1 * (size_t)N_TOT] = acc[i][j][1] + bv[j];
      op[2 * (size_t)N_TOT] = acc[i][j][2] + bv[j];
      op[3 * (size_t)N_TOT] = acc[i][j][3] + bv[j];
    }
  }
}

extern "C" void kernel_launch(void* const* d_in, const int* in_sizes, int n_in,
                              void* d_out, int out_size, void* d_ws, size_t ws_size,
                              hipStream_t stream) {
  const float* x    = (const float*)d_in[0];
  const float* ss   = (const float*)d_in[1];
  const float* wq   = (const float*)d_in[2];
  const float* la   = (const float*)d_in[3];
  const float* lb   = (const float*)d_in[4];
  const float* wsp  = (const float*)d_in[5];
  const float* bias = (const float*)d_in[6];
  float* out = (float*)d_out;

  uint8_t* w = (uint8_t*)d_ws;
  u16* xq  = (u16*)w;  w += (size_t)M_TOT * K_DIN * 2;   // 64 MiB
  u16* xb  = (u16*)w;  w += (size_t)M_TOT * K_DIN * 2;   // 64 MiB
  u16* tb  = (u16*)w;  w += (size_t)M_TOT * RANK * 2;    // 0.5 MiB
  u16* wqb = (u16*)w;  w += (size_t)N_TOT * K_DIN * 2;   // 32 MiB
  u16* wsb = (u16*)w;  w += (size_t)N_TOT * K_DIN * 2;   // 32 MiB
  u16* lbb = (u16*)w;  w += (size_t)N_TOT * RANK * 2;    // 0.25 MiB
  u16* asb = (u16*)w;                                     // 0.25 MiB

  prep_as_k<<<128, 256, 0, stream>>>(la, ss, asb);
  cvt_bf16_k<<<16384, 256, 0, stream>>>(wq,  wqb, (N_TOT * K_DIN) / 4);
  cvt_bf16_k<<<16384, 256, 0, stream>>>(wsp, wsb, (N_TOT * K_DIN) / 4);
  cvt_bf16_k<<<128,   256, 0, stream>>>(lb,  lbb, (N_TOT * RANK) / 4);
  prep_x_k<<<M_TOT, 256, 0, stream>>>(x, ss, xq, xb);
  lora_t_mfma_k<<<M_TOT / 64, 256, 0, stream>>>(xb, asb, tb);
  gemm_k<<<dim3(N_TOT / BN, M_TOT / BM), 256, 0, stream>>>(xq, xb, tb, wqb, wsb, lbb, bias, out);
}

// Round 3
// 602.784 us; speedup vs baseline: 2.1125x; 1.3160x over previous
//
#include <hip/hip_runtime.h>
#include <stdint.h>

typedef float  f32x4  __attribute__((ext_vector_type(4)));
typedef __bf16 bf16x8 __attribute__((ext_vector_type(8)));
typedef unsigned int   u32;
typedef unsigned short u16;
typedef unsigned long long u64;
typedef u32 u32x4 __attribute__((ext_vector_type(4)));

#define M_TOT 8192
#define N_TOT 4096
#define K_DIN 4096
#define RANK  32
#define KPAD  128          // t-path zero-padded to 2 K-tiles
#define NTILE 130          // (2*4096 + 128) / 64

__device__ __forceinline__ u16 f2bf(float f) {
  union { float f; u32 u; } v; v.f = f;
  u32 r = v.u + 0x7fffu + ((v.u >> 16) & 1u);
  return (u16)(r >> 16);
}

// ---- P0: a_sb[r][k] = bf16(lora_a[r][k] * smooth[k])  (32x4096)
__global__ void prep_as_k(const float* __restrict__ la, const float* __restrict__ ss,
                          u16* __restrict__ asb) {
  int i = blockIdx.x * 256 + threadIdx.x;
  f32x4 v = ((const f32x4*)la)[i];
  f32x4 s = ((const f32x4*)ss)[i & 1023];
  f32x4 p = v * s;
  alignas(8) u16 o[4] = { f2bf(p[0]), f2bf(p[1]), f2bf(p[2]), f2bf(p[3]) };
  *(u64*)(asb + 4 * (size_t)i) = *(const u64*)o;
}

// ---- generic fp32 -> bf16 cast (4/thread)
__global__ void cvt_bf16_k(const float* __restrict__ in, u16* __restrict__ out, int n4) {
  int i = blockIdx.x * 256 + threadIdx.x;
  if (i >= n4) return;
  f32x4 v = ((const f32x4*)in)[i];
  alignas(8) u16 o[4] = { f2bf(v[0]), f2bf(v[1]), f2bf(v[2]), f2bf(v[3]) };
  *(u64*)(out + 4 * (size_t)i) = *(const u64*)o;
}

// ---- lora_b [4096][32] fp32 -> bf16 into [4096][KPAD] (cols 0-31; pad pre-zeroed)
__global__ void cvt_lb_k(const float* __restrict__ in, u16* __restrict__ out) {
  int i = blockIdx.x * 256 + threadIdx.x;      // 32768 float4s
  f32x4 v = ((const f32x4*)in)[i];
  int row = i >> 3, c = (i & 7) * 4;
  alignas(8) u16 o[4] = { f2bf(v[0]), f2bf(v[1]), f2bf(v[2]), f2bf(v[3]) };
  *(u64*)(out + (size_t)row * KPAD + c) = *(const u64*)o;
}

// ---- P1: smooth + blockwise fake-quant -> xq (bf16); raw x -> xb (bf16)
__global__ void prep_x_k(const float* __restrict__ x, const float* __restrict__ ss,
                         u16* __restrict__ xq, u16* __restrict__ xb) {
  int m = blockIdx.x;
  int t = threadIdx.x;
  size_t off = (size_t)m * K_DIN + t * 16;
  const f32x4* xp = (const f32x4*)(x + off);
  const f32x4* sp = (const f32x4*)(ss + t * 16);
  float xs[16];
  alignas(16) u16 rb[16], qb[16];
  float amax = 0.0f;
  #pragma unroll
  for (int i = 0; i < 4; ++i) {
    f32x4 a = xp[i], s = sp[i];
    #pragma unroll
    for (int j = 0; j < 4; ++j) {
      float xr = a[j];
      float v  = xr * s[j];
      xs[i*4+j] = v;
      amax = fmaxf(amax, fabsf(v));
      rb[i*4+j] = f2bf(xr);
    }
  }
  amax = fmaxf(amax, 1e-12f);
  float scale = amax / 7.0f;
  #pragma unroll
  for (int i = 0; i < 16; ++i) {
    float r = rintf(xs[i] / scale);
    r = fminf(7.0f, fmaxf(-7.0f, r));
    qb[i] = f2bf(r * scale);
  }
  ((u32x4*)(xq + off))[0] = ((const u32x4*)qb)[0];
  ((u32x4*)(xq + off))[1] = ((const u32x4*)qb)[1];
  ((u32x4*)(xb + off))[0] = ((const u32x4*)rb)[0];
  ((u32x4*)(xb + off))[1] = ((const u32x4*)rb)[1];
}

// ---- P2: t[m][r] = sum_k xb[m][k] * a_sb[r][k] via MFMA, into [M][KPAD] (pad pre-zeroed)
__global__ __launch_bounds__(256)
void lora_t_mfma_k(const u16* __restrict__ xb, const u16* __restrict__ asb,
                   u16* __restrict__ tb) {
  const int wave = threadIdx.x >> 6;
  const int lane = threadIdx.x & 63;
  const int lr = lane & 15, lg = lane >> 4;
  const int m0 = blockIdx.x * 64 + wave * 16;
  f32x4 acc0 = {}, acc1 = {};
  for (int k0 = 0; k0 < K_DIN; k0 += 32) {
    bf16x8 a  = *(const bf16x8*)(xb  + (size_t)(m0 + lr) * K_DIN + k0 + lg * 8);
    bf16x8 b0 = *(const bf16x8*)(asb + (size_t)lr        * K_DIN + k0 + lg * 8);
    bf16x8 b1 = *(const bf16x8*)(asb + (size_t)(16 + lr) * K_DIN + k0 + lg * 8);
    acc0 = __builtin_amdgcn_mfma_f32_16x16x32_bf16(a, b0, acc0, 0, 0, 0);
    acc1 = __builtin_amdgcn_mfma_f32_16x16x32_bf16(a, b1, acc1, 0, 0, 0);
  }
  #pragma unroll
  for (int j = 0; j < 4; ++j) {
    const int row = m0 + lg * 4 + j;
    tb[(size_t)row * KPAD + lr]      = f2bf(acc0[j]);
    tb[(size_t)row * KPAD + 16 + lr] = f2bf(acc1[j]);
  }
}

// ================= main GEMM: 256x256 tile, BK=64, 8-phase (T1-T5) =================
__device__ __forceinline__ void gld_lds16(const u16* g, u16* l) {
  __builtin_amdgcn_global_load_lds((const __attribute__((address_space(1))) u32*)g,
                                   (__attribute__((address_space(3))) u32*)l,
                                   16, 0, 0);
}

#define BAR()  asm volatile("s_barrier" ::: "memory")
#define VMW4() asm volatile("s_waitcnt vmcnt(4)" ::: "memory")

// ds-load A-subtile (4 m-frags x 2 ks) / B-subtile (2 n-frags x 2 ks)
#define LDA(bufel, mh) do { _Pragma("unroll")                                        \
  for (int m_ = 0; m_ < 4; ++m_) {                                                   \
    Ar[m_][0] = *(const bf16x8*)(smem + (bufel) + aoff + ((mh)*4+m_)*1024 + blk0);    \
    Ar[m_][1] = *(const bf16x8*)(smem + (bufel) + aoff + ((mh)*4+m_)*1024 + blk1);    \
  } } while (0)

#define LDB(bufel, nh) do { _Pragma("unroll")                                        \
  for (int n_ = 0; n_ < 2; ++n_) {                                                   \
    Br[(nh)*2+n_][0] = *(const bf16x8*)(smem + (bufel) + boff + ((nh)*2+n_)*1024 + blk0); \
    Br[(nh)*2+n_][1] = *(const bf16x8*)(smem + (bufel) + boff + ((nh)*2+n_)*1024 + blk1); \
  } } while (0)

// one C-quadrant: 4m x 2n x 2ks = 16 MFMA, setprio-wrapped (T5)
#define MMQ(mh, nh) do {                                                             \
  __builtin_amdgcn_s_setprio(1);                                                     \
  _Pragma("unroll")                                                                  \
  for (int m_ = 0; m_ < 4; ++m_) { _Pragma("unroll")                                 \
    for (int n_ = 0; n_ < 2; ++n_) {                                                 \
      acc[(mh)*4+m_][(nh)*2+n_] = __builtin_amdgcn_mfma_f32_16x16x32_bf16(           \
          Ar[m_][0], Br[(nh)*2+n_][0], acc[(mh)*4+m_][(nh)*2+n_], 0, 0, 0);          \
      acc[(mh)*4+m_][(nh)*2+n_] = __builtin_amdgcn_mfma_f32_16x16x32_bf16(           \
          Ar[m_][1], Br[(nh)*2+n_][1], acc[(mh)*4+m_][(nh)*2+n_], 0, 0, 0);          \
    } }                                                                              \
  __builtin_amdgcn_s_setprio(0);                                                     \
} while (0)

__global__ __launch_bounds__(512, 2)
void gemm8_k(const u16* __restrict__ xq, const u16* __restrict__ xb,
             const u16* __restrict__ tb, const u16* __restrict__ wqb,
             const u16* __restrict__ wsb, const u16* __restrict__ lbp,
             const float* __restrict__ bias, float* __restrict__ out) {
  extern __shared__ u16 smem[];           // 2 bufs x (A 16384 + B 16384) elems = 128 KiB
  const int tid  = threadIdx.x;
  const int wave = tid >> 6;
  const int lane = tid & 63;
  const int lr = lane & 15, lg = lane >> 4;
  const int wm = wave >> 2, wn = wave & 3;

  // T1: bijective XCD swizzle (512 % 8 == 0)
  const int wg  = blockIdx.x;
  const int swz = (wg & 7) * 64 + (wg >> 3);
  const int m0 = (swz >> 4) * 256;
  const int n0 = (swz & 15) * 256;

  // ds_read addressing (T2 swizzle: 16B-block cb ^= row&7; row&7 == lr&7)
  const int aoff = wm * 8192 + lr * 64;
  const int boff = 16384 + wn * 4096 + lr * 64;
  const int e7   = lr & 7;
  const int blk0 = ((0 + lg) ^ e7) * 8;
  const int blk1 = ((4 + lg) ^ e7) * 8;

  // staging: thread t covers row tid>>3 (of 64-row issue), source col pre-swizzled
  const int srow = tid >> 3;
  const int scol = ((tid & 7) ^ (srow & 7)) * 8;
  const int woff = wave * 512;

  bf16x8 Ar[4][2], Br[4][2];
  f32x4 acc[8][4] = {};

  // stage one half-tile (128 rows x 64 k) = 2 x global_load_lds per wave
  auto stage = [&](int tt, int mat, int h, int bufel) {
    if (tt > NTILE - 1) tt = NTILE - 1;          // junk-clamp (dead data, never read)
    const u16* p; size_t stride; int kof;
    if (tt < 64)       { p = mat ? wqb : xq; stride = 4096; kof = tt * 64; }
    else if (tt < 128) { p = mat ? wsb : xb; stride = 4096; kof = (tt - 64) * 64; }
    else               { p = mat ? lbp : tb; stride = KPAD; kof = (tt - 128) * 64; }
    const int rb = (mat ? n0 : m0) + h * 128 + srow;
    u16* dst = smem + bufel + mat * 16384 + h * 8192 + woff;
    gld_lds16(p + (size_t)rb * stride + kof + scol, dst);
    gld_lds16(p + (size_t)(rb + 64) * stride + kof + scol, dst + 4096);
  };

  // prologue: tile0 full (buf0) + tile1.B (buf1); gate tile0 complete
  stage(0, 0, 0, 0);     stage(0, 0, 1, 0);
  stage(0, 1, 0, 0);     stage(0, 1, 1, 0);
  stage(1, 1, 0, 32768); stage(1, 1, 1, 32768);
  VMW4();                // 12 issued, wait->4: tile0's 8 landed; tile1.B in flight
  BAR();

  for (int it = 0; it < NTILE / 2; ++it) {
    const int a = 2 * it;
    // P1: Q00(a)  | stage b.A0 -> buf1
    LDA(0, 0); LDB(0, 0);
    stage(a + 1, 0, 0, 32768);
    BAR(); MMQ(0, 0); BAR();
    // P2: Q01(a)  | stage b.A1
    LDB(0, 1);
    stage(a + 1, 0, 1, 32768);
    BAR(); MMQ(0, 1); BAR();
    // P3: Q11(a)  | stage (a+2).B0 -> buf0 (buf0.B fully read after P2)
    LDA(0, 1);
    stage(a + 2, 1, 0, 0);
    BAR(); MMQ(1, 1); BAR();
    // P4: Q10(a)  | stage (a+2).B1; gate: tile b complete (8 oldest of 12)
    stage(a + 2, 1, 1, 0);
    VMW4();
    BAR(); MMQ(1, 0); BAR();
    // P5: Q00(b)  | stage (a+2).A0 -> buf0 (buf0.A fully read after P3)
    LDA(32768, 0); LDB(32768, 0);
    stage(a + 2, 0, 0, 0);
    BAR(); MMQ(0, 0); BAR();
    // P6: Q01(b)  | stage (a+2).A1
    LDB(32768, 1);
    stage(a + 2, 0, 1, 0);
    BAR(); MMQ(0, 1); BAR();
    // P7: Q11(b)  | stage (b+2).B0 -> buf1 (buf1.B fully read after P6)
    LDA(32768, 1);
    stage(a + 3, 1, 0, 32768);
    BAR(); MMQ(1, 1); BAR();
    // P8: Q10(b)  | stage (b+2).B1; gate: tile a+2 complete
    stage(a + 3, 1, 1, 32768);
    VMW4();
    BAR(); MMQ(1, 0); BAR();
  }

  // epilogue: bias + store (verified r1 C/D mapping: row=...+lg*4+j, col=...+lr)
  float bv[4];
  #pragma unroll
  for (int n = 0; n < 4; ++n) bv[n] = bias[n0 + wn * 64 + n * 16 + lr];
  #pragma unroll
  for (int m = 0; m < 8; ++m) {
    const int row = m0 + wm * 128 + m * 16 + lg * 4;
    #pragma unroll
    for (int n = 0; n < 4; ++n) {
      const int col = n0 + wn * 64 + n * 16 + lr;
      float* op = out + (size_t)row * N_TOT + col;
      op[0 * (size_t)N_TOT] = acc[m][n][0] + bv[n];
      op[1 * (size_t)N_TOT] = acc[m][n][1] + bv[n];
      op[2 * (size_t)N_TOT] = acc[m][n][2] + bv[n];
      op[3 * (size_t)N_TOT] = acc[m][n][3] + bv[n];
    }
  }
}

extern "C" void kernel_launch(void* const* d_in, const int* in_sizes, int n_in,
                              void* d_out, int out_size, void* d_ws, size_t ws_size,
                              hipStream_t stream) {
  const float* x    = (const float*)d_in[0];
  const float* ss   = (const float*)d_in[1];
  const float* wq   = (const float*)d_in[2];
  const float* la   = (const float*)d_in[3];
  const float* lb   = (const float*)d_in[4];
  const float* wsp  = (const float*)d_in[5];
  const float* bias = (const float*)d_in[6];
  float* out = (float*)d_out;

  uint8_t* w = (uint8_t*)d_ws;
  u16* xq   = (u16*)w;  w += (size_t)M_TOT * K_DIN * 2;   // 64 MiB
  u16* xb   = (u16*)w;  w += (size_t)M_TOT * K_DIN * 2;   // 64 MiB
  u16* wqb  = (u16*)w;  w += (size_t)N_TOT * K_DIN * 2;   // 32 MiB
  u16* wsb  = (u16*)w;  w += (size_t)N_TOT * K_DIN * 2;   // 32 MiB
  u16* tb   = (u16*)w;  w += (size_t)M_TOT * KPAD * 2;    // 2 MiB  (adjacent: one memset)
  u16* lbp  = (u16*)w;  w += (size_t)N_TOT * KPAD * 2;    // 1 MiB
  u16* asb  = (u16*)w;                                     // 0.25 MiB

  hipMemsetAsync(tb, 0, ((size_t)M_TOT + N_TOT) * KPAD * 2, stream);
  prep_as_k<<<128, 256, 0, stream>>>(la, ss, asb);
  cvt_bf16_k<<<16384, 256, 0, stream>>>(wq,  wqb, (N_TOT * K_DIN) / 4);
  cvt_bf16_k<<<16384, 256, 0, stream>>>(wsp, wsb, (N_TOT * K_DIN) / 4);
  cvt_lb_k<<<128, 256, 0, stream>>>(lb, lbp);
  prep_x_k<<<M_TOT, 256, 0, stream>>>(x, ss, xq, xb);
  lora_t_mfma_k<<<M_TOT / 64, 256, 0, stream>>>(xb, asb, tb);

  hipFuncSetAttribute((const void*)gemm8_k,
                      hipFuncAttributeMaxDynamicSharedMemorySize, 131072);
  gemm8_k<<<dim3((N_TOT / 256) * (M_TOT / 256)), 512, 131072, stream>>>(
      xq, xb, tb, wqb, wsb, lbp, bias, out);
}